// Round 14
// baseline (211.977 us; speedup 1.0000x reference)
//
#include <hip/hip_runtime.h>
#include <hip/hip_bf16.h>
#include <stdint.h>

typedef __bf16 bf16;
typedef __bf16 bf16x4 __attribute__((ext_vector_type(4)));
typedef __bf16 bf16x8 __attribute__((ext_vector_type(8)));
typedef float  f32x4  __attribute__((ext_vector_type(4)));

#define D_MODEL 1024
#define N_HEADS 16
#define HEAD_DIM 64
#define SEQ 2048
#define BATCH 2
#define LOG2E 1.4426950408889634f
#define NEG_SENT -3.0e4f   // finite "-inf": exp2 underflows to 0; never NaNs
#define CAP 24.0f          // fixed softmax cap (log2 domain); |s*SC| << 127-24

__device__ __forceinline__ bf16x8 ld8(const bf16* p) { return *(const bf16x8*)p; }

__device__ __forceinline__ void async16(const bf16* g, bf16* l) {
  __builtin_amdgcn_global_load_lds(
      (const __attribute__((address_space(1))) void*)g,
      (__attribute__((address_space(3))) void*)l, 16, 0, 0);
}

// ---------------- fused prep: x fp32->bf16 convert + both weight transposes ----------------
__global__ __launch_bounds__(256)
void prep(const float* __restrict__ x, bf16* __restrict__ x16,
          const float* __restrict__ Wqkv, bf16* __restrict__ Wqkv_t,
          const float* __restrict__ Wout, bf16* __restrict__ Wout_t) {
  __shared__ float tile[32][33];
  const int blk = blockIdx.x, tid = threadIdx.x;
  if (blk < 4096) {
    int i = (blk * 256 + tid) * 4;
    float4 v = *(const float4*)&x[i];
    bf16 o[4] = {(bf16)v.x, (bf16)v.y, (bf16)v.z, (bf16)v.w};
    *(uint2*)&x16[i] = *(uint2*)o;
    return;
  }
  const float* in; bf16* out; int R, C, c0, r0;
  if (blk < 7168) {
    int b = blk - 4096;
    in = Wqkv; out = Wqkv_t; R = 1024; C = 3072;
    c0 = (b % 96) * 32; r0 = (b / 96) * 32;
  } else {
    int b = blk - 7168;
    in = Wout; out = Wout_t; R = 1024; C = 1024;
    c0 = (b % 32) * 32; r0 = (b / 32) * 32;
  }
  const int tx = tid & 31, ty = tid >> 5;
  #pragma unroll
  for (int i = 0; i < 32; i += 8)
    tile[ty + i][tx] = in[(size_t)(r0 + ty + i) * C + c0 + tx];
  __syncthreads();
  #pragma unroll
  for (int i = 0; i < 32; i += 8)
    out[(size_t)(c0 + ty + i) * R + r0 + tx] = (bf16)tile[tx][ty + i];
}

// ---------------- GEMM v21: v13 loop (BK=32) + ISOLATED Q/K LDS-bounce epilogue ----------------
// v14/v15 bundled the bounce with the BK=64 bank-conflict regression; its isolated
// sign is unknown (v15's +7.3us residual could be either lever). This version tests
// the bounce ALONE: K-loop and staging identical to v13; only the mode-0 Q/K store
// path changes from 64 scalar 2B stores/thread (32B segments) to an 18.4KB LDS
// bounce (stride 72 = 144B, 16B-aligned -- v20's alignment lesson) + contiguous
// b128 stores. V^T and mode-1 paths unchanged.
__global__ __launch_bounds__(256)
void gemm_bt(const bf16* __restrict__ A, const bf16* __restrict__ Bt,
             const float* __restrict__ bias, float* __restrict__ outf,
             bf16* __restrict__ Qp, bf16* __restrict__ Kp, bf16* __restrict__ Vtp,
             int N, int mode) {
  __shared__ __align__(16) char arena[18432];      // staging 16K; bounce [128][72] 18.4K
  bf16* shA = (bf16*)arena;
  bf16* shB = (bf16*)(arena + 8192);
  const int tid  = threadIdx.x;
  const int bm0  = blockIdx.y * 128, bn0 = blockIdx.x * 128;
  const int wave = tid >> 6, lane = tid & 63;
  const int quad = lane >> 4, l16 = lane & 15;
  const int wm = (wave >> 1) * 64, wn = (wave & 1) * 64;

  const int c_lo  = tid;
  const int row_lo = c_lo >> 2,  col_lo = (c_lo & 3) << 3;
  const int c_hi  = tid + 256;
  const int row_hi = c_hi >> 2,  col_hi = (c_hi & 3) << 3;
  const int cb_lo = (wave * 64) * 8;
  const int cb_hi = (256 + wave * 64) * 8;

  f32x4 acc[4][4];
  #pragma unroll
  for (int i = 0; i < 4; i++)
    #pragma unroll
    for (int j = 0; j < 4; j++)
      acc[i][j] = (f32x4){0.f, 0.f, 0.f, 0.f};

  for (int k0 = 0; k0 < 1024; k0 += 32) {
    async16(&A[(size_t)(bm0 + row_lo) * 1024 + k0 + col_lo], &shA[cb_lo]);
    async16(&A[(size_t)(bm0 + row_hi) * 1024 + k0 + col_hi], &shA[cb_hi]);
    async16(&Bt[(size_t)(bn0 + row_lo) * 1024 + k0 + col_lo], &shB[cb_lo]);
    async16(&Bt[(size_t)(bn0 + row_hi) * 1024 + k0 + col_hi], &shB[cb_hi]);
    __syncthreads();
    bf16x8 af[4], bg[4];
    #pragma unroll
    for (int i = 0; i < 4; i++)
      af[i] = ld8(&shA[(wm + i * 16 + l16) * 32 + quad * 8]);
    #pragma unroll
    for (int j = 0; j < 4; j++)
      bg[j] = ld8(&shB[(wn + j * 16 + l16) * 32 + quad * 8]);
    #pragma unroll
    for (int i = 0; i < 4; i++)
      #pragma unroll
      for (int j = 0; j < 4; j++)
        acc[i][j] = __builtin_amdgcn_mfma_f32_16x16x32_bf16(af[i], bg[j], acc[i][j], 0, 0, 0);
    __syncthreads();
  }

  // ---- epilogue; C/D layout: col = lane&15, row = quad*4 + reg [verified m89/m91] ----
  const int which = bn0 >> 10;                      // block-uniform: 0=Q 1=K 2=V
  const int b = bm0 >> 11, t0 = bm0 & 2047;

  if (mode == 1) {
    #pragma unroll
    for (int i = 0; i < 4; i++) {
      #pragma unroll
      for (int j = 0; j < 4; j++) {
        int gn = bn0 + wn + j * 16 + l16;
        float bv = bias[gn];
        int gm0 = bm0 + wm + i * 16 + quad * 4;
        #pragma unroll
        for (int r = 0; r < 4; r++)
          outf[(size_t)(gm0 + r) * N + gn] = acc[i][j][r] + bv;
      }
    }
  } else if (which == 2) {
    // V^T: lane holds 4 consecutive t at fixed d -> one 8B store (unchanged)
    #pragma unroll
    for (int i = 0; i < 4; i++) {
      #pragma unroll
      for (int j = 0; j < 4; j++) {
        int gn = bn0 + wn + j * 16 + l16;
        float bv = bias[gn];
        int rem = gn & 1023;
        int h = rem >> 6, d = rem & 63;
        int gm0 = bm0 + wm + i * 16 + quad * 4;
        int tt = gm0 & 2047;
        int bh = b * N_HEADS + h;
        bf16x4 vv = {(bf16)(acc[i][j][0] + bv), (bf16)(acc[i][j][1] + bv),
                     (bf16)(acc[i][j][2] + bv), (bf16)(acc[i][j][3] + bv)};
        *(bf16x4*)&Vtp[((size_t)bh * 64 + d) * SEQ + tt] = vv;
      }
    }
  } else {
    // Q or K: bounce -> fully contiguous 16KB store per head
    bf16* Cb = (bf16*)arena;                        // [128][72] bf16, 144B rows (16B-aligned)
    const int hbase = (bn0 & 1023) >> 6;            // half h -> head hbase+h
    bf16* dst = (which == 0) ? Qp : Kp;
    #pragma unroll
    for (int h = 0; h < 2; h++) {
      if ((wave & 1) == h) {
        #pragma unroll
        for (int i = 0; i < 4; i++)
          #pragma unroll
          for (int j = 0; j < 4; j++) {
            float bv = bias[bn0 + h * 64 + j * 16 + l16];
            #pragma unroll
            for (int r = 0; r < 4; r++)
              Cb[(wm + i * 16 + quad * 4 + r) * 72 + j * 16 + l16] =
                  (bf16)(acc[i][j][r] + bv);
          }
      }
      __syncthreads();
      const size_t base = ((size_t)(b * N_HEADS + hbase + h) * SEQ + t0) * 64;
      #pragma unroll
      for (int k = 0; k < 4; k++) {
        int u = k * 256 + tid;                      // 1024 16B units
        int row = u >> 3, ch = u & 7;
        *(bf16x8*)&dst[base + (size_t)row * 64 + ch * 8] = ld8(&Cb[row * 72 + ch * 8]);
      }
      __syncthreads();
    }
  }
}

// ---------------- gemm_out v17: output projection, 64x128 tiles -> 512 blocks ----------------
__global__ __launch_bounds__(256)
void gemm_out(const bf16* __restrict__ A, const bf16* __restrict__ Bt,
              const float* __restrict__ bias, float* __restrict__ outf) {
  __shared__ __align__(16) bf16 shA[64 * 32];     // 4 KB
  __shared__ __align__(16) bf16 shB[128 * 32];    // 8 KB
  const int tid  = threadIdx.x;
  const int bm0  = blockIdx.y * 64, bn0 = blockIdx.x * 128;
  const int wave = tid >> 6, lane = tid & 63;
  const int quad = lane >> 4, l16 = lane & 15;
  const int wn = wave * 32;

  f32x4 acc[4][2];
  #pragma unroll
  for (int i = 0; i < 4; i++)
    #pragma unroll
    for (int j = 0; j < 2; j++)
      acc[i][j] = (f32x4){0.f, 0.f, 0.f, 0.f};

  const int srow = tid >> 2, scol = (tid & 3) << 3;   // 64 rows x 32 cols per issue set
  for (int k0 = 0; k0 < 1024; k0 += 32) {
    async16(&A[(size_t)(bm0 + srow) * 1024 + k0 + scol], &shA[tid * 8]);
    async16(&Bt[(size_t)(bn0 + srow) * 1024 + k0 + scol], &shB[tid * 8]);
    async16(&Bt[(size_t)(bn0 + 64 + srow) * 1024 + k0 + scol], &shB[(256 + tid) * 8]);
    __syncthreads();
    bf16x8 af[4], bg[2];
    #pragma unroll
    for (int i = 0; i < 4; i++)
      af[i] = ld8(&shA[(i * 16 + l16) * 32 + quad * 8]);
    #pragma unroll
    for (int j = 0; j < 2; j++)
      bg[j] = ld8(&shB[(wn + j * 16 + l16) * 32 + quad * 8]);
    #pragma unroll
    for (int i = 0; i < 4; i++)
      #pragma unroll
      for (int j = 0; j < 2; j++)
        acc[i][j] = __builtin_amdgcn_mfma_f32_16x16x32_bf16(af[i], bg[j], acc[i][j], 0, 0, 0);
    __syncthreads();
  }

  // epilogue; C/D layout: col = lane&15, row = quad*4 + reg
  #pragma unroll
  for (int i = 0; i < 4; i++) {
    #pragma unroll
    for (int j = 0; j < 2; j++) {
      int gn = bn0 + wn + j * 16 + l16;
      float bv = bias[gn];
      int gm0 = bm0 + i * 16 + quad * 4;
      #pragma unroll
      for (int r = 0; r < 4; r++)
        outf[(size_t)(gm0 + r) * D_MODEL + gn] = acc[i][j][r] + bv;
    }
  }
}

// ---------------- flash attention (causal) v16 EXACT (63.2us best): 4 waves x 32 q ----------------
// v20 post-mortem: stride-68 PT rows (136B) broke 16B alignment -> b128 reads split;
// V-hoist added 16 VGPR for nothing. Reverted byte-identical to v16 (stride 72 =
// 144B = 16B-aligned; V reads in PV position). attn polish retired: 63us is
// conflict-free and latency-bound at this structure.
__global__ __launch_bounds__(256)
void attn_k(const bf16* __restrict__ Qp, const bf16* __restrict__ Kp,
            const bf16* __restrict__ Vtp, bf16* __restrict__ Obuf) {
  __shared__ __align__(16) bf16 shK[2][64 * 64];   // [buf][key][swizzled d-chunk]
  __shared__ __align__(16) bf16 shV[2][64 * 64];   // [buf][d][swizzled key-chunk]
  __shared__ __align__(16) bf16 shPT[4][32 * 72];  // per-wave P^T scratch (2 groups)
  const int tid  = threadIdx.x;
  const int wave = tid >> 6, lane = tid & 63;
  const int quad = lane >> 4, l16 = lane & 15;
  const int bx = blockIdx.x;
  const int g = bx >> 5;
  const int qb = (g < 8) ? g : 23 - g;   // complementary pairing
  const int bh = bx & 31;                // same-head blocks: id stride 32 -> same XCD
  const int qw0 = qb * 128 + wave * 32;  // first of this wave's 32 q rows

  const bf16* Qbh = Qp  + (size_t)bh * SEQ * 64;
  const bf16* Kbh = Kp  + (size_t)bh * SEQ * 64;
  const bf16* Vbh = Vtp + (size_t)bh * 64 * SEQ;

  // staging: 256 threads, 2 K + 2 V 16B issues each per step (v11 pattern)
  const int kr_s = tid >> 3, kc_s = tid & 7;

  // Q as B-operand frags, two 16-row groups
  bf16x8 aQ[2][2];
  #pragma unroll
  for (int g2 = 0; g2 < 2; g2++)
    #pragma unroll
    for (int p = 0; p < 2; p++)
      aQ[g2][p] = ld8(&Qbh[(size_t)(qw0 + g2 * 16 + l16) * 64 + p * 32 + quad * 8]);

  f32x4 o0[4], o1[4];
  #pragma unroll
  for (int j = 0; j < 4; j++) { o0[j] = (f32x4){0.f,0.f,0.f,0.f}; o1[j] = (f32x4){0.f,0.f,0.f,0.f}; }
  f32x4 lacc0 = (f32x4){0.f,0.f,0.f,0.f}, lacc1 = (f32x4){0.f,0.f,0.f,0.f};
  const int qlane0 = qw0 + l16, qlane1 = qw0 + 16 + l16;
  const int xq = l16 & 7;             // read-side swizzle key

  const float SC = 0.125f * LOG2E;
  bf16* PT = shPT[wave];

  // ---- prologue: stage step 0 into buf 0 ----
  #pragma unroll
  for (int i = 0; i < 2; i++) {
    int kr = kr_s + i * 32;
    async16(&Kbh[(size_t)kr * 64 + (kc_s ^ (kr & 7)) * 8], &shK[0][(kr * 8 + kc_s) * 8]);
    async16(&Vbh[(size_t)kr * SEQ + (kc_s ^ (kr & 7)) * 8], &shV[0][(kr * 8 + kc_s) * 8]);
  }
  __syncthreads();   // drains vmcnt -> step 0 resident

  const int NS = 2 * qb + 2;          // 64-key steps (keys 0 .. qb*128+127)
  int cur = 0;
  for (int s = 0; s < NS; s++) {
    // ---- issue stage of step s+1 into buf^1 (hidden under this step's compute) ----
    if (s + 1 < NS) {
      const int kb1 = (s + 1) * 64;
      #pragma unroll
      for (int i = 0; i < 2; i++) {
        int kr = kr_s + i * 32;
        async16(&Kbh[(size_t)(kb1 + kr) * 64 + (kc_s ^ (kr & 7)) * 8],
                &shK[cur ^ 1][(kr * 8 + kc_s) * 8]);
        async16(&Vbh[(size_t)kr * SEQ + kb1 + (kc_s ^ (kr & 7)) * 8],
                &shV[cur ^ 1][(kr * 8 + kc_s) * 8]);
      }
    }

    const int hb = s * 64;
    if (hb <= qw0 + 31) {              // wave-uniform active guard (no barrier inside)
      const bf16* Kb = shK[cur];
      const bf16* Vb = shV[cur];

      // ---- S^T = K*Q^T, both q-groups off the SAME K-frag reads ----
      f32x4 st0[4], st1[4];
      __builtin_amdgcn_s_setprio(1);
      #pragma unroll
      for (int c = 0; c < 4; c++) {
        int kr0 = c * 16 + l16;                      // kr0&7 == xq
        bf16x8 kf0 = ld8(&Kb[kr0 * 64 + ((quad    ) ^ xq) * 8]);
        bf16x8 kf1 = ld8(&Kb[kr0 * 64 + ((quad + 4) ^ xq) * 8]);
        f32x4 a0 = (f32x4){0.f,0.f,0.f,0.f};
        a0 = __builtin_amdgcn_mfma_f32_16x16x32_bf16(kf0, aQ[0][0], a0, 0, 0, 0);
        a0 = __builtin_amdgcn_mfma_f32_16x16x32_bf16(kf1, aQ[0][1], a0, 0, 0, 0);
        f32x4 a1 = (f32x4){0.f,0.f,0.f,0.f};
        a1 = __builtin_amdgcn_mfma_f32_16x16x32_bf16(kf0, aQ[1][0], a1, 0, 0, 0);
        a1 = __builtin_amdgcn_mfma_f32_16x16x32_bf16(kf1, aQ[1][1], a1, 0, 0, 0);
        st0[c] = a0; st1[c] = a1;      // row=key-local(quad*4+r), col=q(l16)
      }
      __builtin_amdgcn_s_setprio(0);

      // ---- causal mask (diagonal-straddling steps only; wave-uniform) ----
      if (hb + 63 > qw0) {
        #pragma unroll
        for (int c = 0; c < 4; c++)
          #pragma unroll
          for (int r = 0; r < 4; r++) {
            int key = hb + c * 16 + quad * 4 + r;
            if (key > qlane0) st0[c][r] = NEG_SENT;
            if (key > qlane1) st1[c][r] = NEG_SENT;
          }
      }

      // ---- fixed-cap softmax, both groups ----
      #pragma unroll
      for (int c = 0; c < 4; c++) {
        #pragma unroll
        for (int r = 0; r < 4; r++) {
          st0[c][r] = exp2f(__builtin_fmaf(st0[c][r], SC, -CAP));
          st1[c][r] = exp2f(__builtin_fmaf(st1[c][r], SC, -CAP));
        }
        lacc0 += st0[c]; lacc1 += st1[c];
      }

      // ---- P^T -> per-wave LDS (one wait for both groups) ----
      #pragma unroll
      for (int c = 0; c < 4; c++) {
        bf16x4 p0 = {(bf16)st0[c][0], (bf16)st0[c][1], (bf16)st0[c][2], (bf16)st0[c][3]};
        bf16x4 p1 = {(bf16)st1[c][0], (bf16)st1[c][1], (bf16)st1[c][2], (bf16)st1[c][3]};
        *(bf16x4*)&PT[l16 * 72 + c * 16 + quad * 4] = p0;
        *(bf16x4*)&PT[(16 + l16) * 72 + c * 16 + quad * 4] = p1;
      }
      asm volatile("s_waitcnt lgkmcnt(0)" ::: "memory");  // cross-lane RAW within wave
      bf16x8 bP00 = ld8(&PT[l16 * 72 + quad * 8]);
      bf16x8 bP01 = ld8(&PT[l16 * 72 + 32 + quad * 8]);
      bf16x8 bP10 = ld8(&PT[(16 + l16) * 72 + quad * 8]);
      bf16x8 bP11 = ld8(&PT[(16 + l16) * 72 + 32 + quad * 8]);

      // ---- O^T += V^T * P^T, both groups off the SAME V-frag reads ----
      __builtin_amdgcn_s_setprio(1);
      #pragma unroll
      for (int j = 0; j < 4; j++) {
        int d = j * 16 + l16;                        // d&7 == xq
        bf16x8 v0 = ld8(&Vb[d * 64 + ((quad    ) ^ xq) * 8]);
        bf16x8 v1 = ld8(&Vb[d * 64 + ((quad + 4) ^ xq) * 8]);
        o0[j] = __builtin_amdgcn_mfma_f32_16x16x32_bf16(v0, bP00, o0[j], 0, 0, 0);
        o0[j] = __builtin_amdgcn_mfma_f32_16x16x32_bf16(v1, bP01, o0[j], 0, 0, 0);
        o1[j] = __builtin_amdgcn_mfma_f32_16x16x32_bf16(v0, bP10, o1[j], 0, 0, 0);
        o1[j] = __builtin_amdgcn_mfma_f32_16x16x32_bf16(v1, bP11, o1[j], 0, 0, 0);
      }
      __builtin_amdgcn_s_setprio(0);
    }

    __syncthreads();   // drains vmcnt+lgkm -> step s+1 resident; buf^1 readers done
    cur ^= 1;
  }

  // ---- final l reduction + store, both groups ----
  const int b = bh >> 4, h = bh & 15;
  {
    float lr0 = (lacc0[0] + lacc0[1]) + (lacc0[2] + lacc0[3]);
    lr0 += __shfl_xor(lr0, 16, 64);
    lr0 += __shfl_xor(lr0, 32, 64);
    float lr1 = (lacc1[0] + lacc1[1]) + (lacc1[2] + lacc1[3]);
    lr1 += __shfl_xor(lr1, 16, 64);
    lr1 += __shfl_xor(lr1, 32, 64);
    float inv0 = 1.0f / lr0, inv1 = 1.0f / lr1;
    size_t base0 = ((size_t)(b * SEQ + qw0 + l16)) * D_MODEL + h * 64;
    size_t base1 = ((size_t)(b * SEQ + qw0 + 16 + l16)) * D_MODEL + h * 64;
    #pragma unroll
    for (int j = 0; j < 4; j++) {
      bf16x4 ov0 = {(bf16)(o0[j][0] * inv0), (bf16)(o0[j][1] * inv0),
                    (bf16)(o0[j][2] * inv0), (bf16)(o0[j][3] * inv0)};
      bf16x4 ov1 = {(bf16)(o1[j][0] * inv1), (bf16)(o1[j][1] * inv1),
                    (bf16)(o1[j][2] * inv1), (bf16)(o1[j][3] * inv1)};
      *(bf16x4*)&Obuf[base0 + j * 16 + quad * 4] = ov0;
      *(bf16x4*)&Obuf[base1 + j * 16 + quad * 4] = ov1;
    }
  }
}

extern "C" void kernel_launch(void* const* d_in, const int* in_sizes, int n_in,
                              void* d_out, int out_size, void* d_ws, size_t ws_size,
                              hipStream_t stream) {
  const float* x    = (const float*)d_in[0];   // (2,2048,1024) fp32
  const float* Wqkv = (const float*)d_in[1];   // (1024,3072)  fp32
  const float* bqkv = (const float*)d_in[2];   // (3072,)      fp32
  const float* Wout = (const float*)d_in[3];   // (1024,1024)  fp32
  const float* bout = (const float*)d_in[4];   // (1024,)      fp32
  float* out = (float*)d_out;                  // (2,2048,1024) fp32

  char* ws = (char*)d_ws;
  bf16* x16    = (bf16*)(ws);                     //  8 MB; reused as Obuf after gemm0
  bf16* Wqkv_t = (bf16*)(ws + 8388608);           //  6 MB
  bf16* Wout_t = (bf16*)(ws + 14680064);          //  2 MB
  bf16* Qp     = (bf16*)(ws + 16777216);          //  8 MB
  bf16* Kp     = (bf16*)(ws + 25165824);          //  8 MB
  bf16* Vtp    = (bf16*)(ws + 33554432);          //  8 MB  -> total 40 MB
  bf16* Obuf   = x16;

  prep<<<8192, 256, 0, stream>>>(x, x16, Wqkv, Wqkv_t, Wout, Wout_t);

  gemm_bt<<<dim3(3072 / 128, 4096 / 128), 256, 0, stream>>>(
      x16, Wqkv_t, bqkv, nullptr, Qp, Kp, Vtp, 3072, 0);

  attn_k<<<dim3(512), 256, 0, stream>>>(Qp, Kp, Vtp, Obuf);

  gemm_out<<<dim3(1024 / 128, 4096 / 64), 256, 0, stream>>>(
      Obuf, Wout_t, bout, out);
}

// Round 15
// 189.516 us; speedup vs baseline: 1.1185x; 1.1185x over previous
//
#include <hip/hip_runtime.h>
#include <hip/hip_bf16.h>
#include <stdint.h>

typedef __bf16 bf16;
typedef __bf16 bf16x4 __attribute__((ext_vector_type(4)));
typedef __bf16 bf16x8 __attribute__((ext_vector_type(8)));
typedef float  f32x4  __attribute__((ext_vector_type(4)));

#define D_MODEL 1024
#define N_HEADS 16
#define HEAD_DIM 64
#define SEQ 2048
#define BATCH 2
#define LOG2E 1.4426950408889634f
#define NEG_SENT -3.0e4f   // finite "-inf": exp2 underflows to 0; never NaNs
#define CAP 24.0f          // fixed softmax cap (log2 domain); |s*SC| << 127-24

__device__ __forceinline__ bf16x8 ld8(const bf16* p) { return *(const bf16x8*)p; }

__device__ __forceinline__ void async16(const bf16* g, bf16* l) {
  __builtin_amdgcn_global_load_lds(
      (const __attribute__((address_space(1))) void*)g,
      (__attribute__((address_space(3))) void*)l, 16, 0, 0);
}

// ---------------- fused prep: x fp32->bf16 convert + both weight transposes ----------------
__global__ __launch_bounds__(256)
void prep(const float* __restrict__ x, bf16* __restrict__ x16,
          const float* __restrict__ Wqkv, bf16* __restrict__ Wqkv_t,
          const float* __restrict__ Wout, bf16* __restrict__ Wout_t) {
  __shared__ float tile[32][33];
  const int blk = blockIdx.x, tid = threadIdx.x;
  if (blk < 4096) {
    int i = (blk * 256 + tid) * 4;
    float4 v = *(const float4*)&x[i];
    bf16 o[4] = {(bf16)v.x, (bf16)v.y, (bf16)v.z, (bf16)v.w};
    *(uint2*)&x16[i] = *(uint2*)o;
    return;
  }
  const float* in; bf16* out; int R, C, c0, r0;
  if (blk < 7168) {
    int b = blk - 4096;
    in = Wqkv; out = Wqkv_t; R = 1024; C = 3072;
    c0 = (b % 96) * 32; r0 = (b / 96) * 32;
  } else {
    int b = blk - 7168;
    in = Wout; out = Wout_t; R = 1024; C = 1024;
    c0 = (b % 32) * 32; r0 = (b / 32) * 32;
  }
  const int tx = tid & 31, ty = tid >> 5;
  #pragma unroll
  for (int i = 0; i < 32; i += 8)
    tile[ty + i][tx] = in[(size_t)(r0 + ty + i) * C + c0 + tx];
  __syncthreads();
  #pragma unroll
  for (int i = 0; i < 32; i += 8)
    out[(size_t)(c0 + ty + i) * R + r0 + tx] = (bf16)tile[tx][ty + i];
}

// ---------------- GEMM (v13 EXACT, reverted): BK=32, m97-style staging ----------------
// v21 post-mortem: isolated Q/K LDS-bounce = +20us regression (scatter stores were
// never the cost; L2 absorbs them). GEMM epilogue experiments closed.
__global__ __launch_bounds__(256)
void gemm_bt(const bf16* __restrict__ A, const bf16* __restrict__ Bt,
             const float* __restrict__ bias, float* __restrict__ outf,
             bf16* __restrict__ Qp, bf16* __restrict__ Kp, bf16* __restrict__ Vtp,
             int N, int mode) {
  __shared__ __align__(16) bf16 shA[128 * 32];
  __shared__ __align__(16) bf16 shB[128 * 32];
  const int tid  = threadIdx.x;
  const int bm0  = blockIdx.y * 128, bn0 = blockIdx.x * 128;
  const int wave = tid >> 6, lane = tid & 63;
  const int quad = lane >> 4, l16 = lane & 15;
  const int wm = (wave >> 1) * 64, wn = (wave & 1) * 64;

  const int c_lo  = tid;
  const int row_lo = c_lo >> 2,  col_lo = (c_lo & 3) << 3;
  const int c_hi  = tid + 256;
  const int row_hi = c_hi >> 2,  col_hi = (c_hi & 3) << 3;
  const int cb_lo = (wave * 64) * 8;
  const int cb_hi = (256 + wave * 64) * 8;

  f32x4 acc[4][4];
  #pragma unroll
  for (int i = 0; i < 4; i++)
    #pragma unroll
    for (int j = 0; j < 4; j++)
      acc[i][j] = (f32x4){0.f, 0.f, 0.f, 0.f};

  for (int k0 = 0; k0 < 1024; k0 += 32) {
    async16(&A[(size_t)(bm0 + row_lo) * 1024 + k0 + col_lo], &shA[cb_lo]);
    async16(&A[(size_t)(bm0 + row_hi) * 1024 + k0 + col_hi], &shA[cb_hi]);
    async16(&Bt[(size_t)(bn0 + row_lo) * 1024 + k0 + col_lo], &shB[cb_lo]);
    async16(&Bt[(size_t)(bn0 + row_hi) * 1024 + k0 + col_hi], &shB[cb_hi]);
    __syncthreads();
    bf16x8 af[4], bg[4];
    #pragma unroll
    for (int i = 0; i < 4; i++)
      af[i] = ld8(&shA[(wm + i * 16 + l16) * 32 + quad * 8]);
    #pragma unroll
    for (int j = 0; j < 4; j++)
      bg[j] = ld8(&shB[(wn + j * 16 + l16) * 32 + quad * 8]);
    #pragma unroll
    for (int i = 0; i < 4; i++)
      #pragma unroll
      for (int j = 0; j < 4; j++)
        acc[i][j] = __builtin_amdgcn_mfma_f32_16x16x32_bf16(af[i], bg[j], acc[i][j], 0, 0, 0);
    __syncthreads();
  }

  // epilogue; C/D layout: col = lane&15, row = quad*4 + reg   [verified m89/m91]
  #pragma unroll
  for (int i = 0; i < 4; i++) {
    #pragma unroll
    for (int j = 0; j < 4; j++) {
      int gn = bn0 + wn + j * 16 + l16;
      float bv = bias[gn];
      int gm0 = bm0 + wm + i * 16 + quad * 4;
      if (mode == 1) {
        #pragma unroll
        for (int r = 0; r < 4; r++)
          outf[(size_t)(gm0 + r) * N + gn] = acc[i][j][r] + bv;
      } else {
        int which = gn >> 10, rem = gn & 1023;   // uniform across lanes per j
        int h = rem >> 6, d = rem & 63;
        int b = gm0 >> 11, t0 = gm0 & 2047;
        int bh = b * N_HEADS + h;
        if (which == 2) {
          bf16x4 vv = {(bf16)(acc[i][j][0] + bv), (bf16)(acc[i][j][1] + bv),
                       (bf16)(acc[i][j][2] + bv), (bf16)(acc[i][j][3] + bv)};
          *(bf16x4*)&Vtp[((size_t)bh * 64 + d) * SEQ + t0] = vv;
        } else {
          bf16* dst = (which == 0) ? Qp : Kp;
          #pragma unroll
          for (int r = 0; r < 4; r++)
            dst[((size_t)bh * SEQ + t0 + r) * 64 + d] = (bf16)(acc[i][j][r] + bv);
        }
      }
    }
  }
}

// ---------------- gemm_out v17: output projection, 64x128 tiles -> 512 blocks ----------------
__global__ __launch_bounds__(256)
void gemm_out(const bf16* __restrict__ A, const bf16* __restrict__ Bt,
              const float* __restrict__ bias, float* __restrict__ outf) {
  __shared__ __align__(16) bf16 shA[64 * 32];     // 4 KB
  __shared__ __align__(16) bf16 shB[128 * 32];    // 8 KB
  const int tid  = threadIdx.x;
  const int bm0  = blockIdx.y * 64, bn0 = blockIdx.x * 128;
  const int wave = tid >> 6, lane = tid & 63;
  const int quad = lane >> 4, l16 = lane & 15;
  const int wn = wave * 32;

  f32x4 acc[4][2];
  #pragma unroll
  for (int i = 0; i < 4; i++)
    #pragma unroll
    for (int j = 0; j < 2; j++)
      acc[i][j] = (f32x4){0.f, 0.f, 0.f, 0.f};

  const int srow = tid >> 2, scol = (tid & 3) << 3;   // 64 rows x 32 cols per issue set
  for (int k0 = 0; k0 < 1024; k0 += 32) {
    async16(&A[(size_t)(bm0 + srow) * 1024 + k0 + scol], &shA[tid * 8]);
    async16(&Bt[(size_t)(bn0 + srow) * 1024 + k0 + scol], &shB[tid * 8]);
    async16(&Bt[(size_t)(bn0 + 64 + srow) * 1024 + k0 + scol], &shB[(256 + tid) * 8]);
    __syncthreads();
    bf16x8 af[4], bg[2];
    #pragma unroll
    for (int i = 0; i < 4; i++)
      af[i] = ld8(&shA[(i * 16 + l16) * 32 + quad * 8]);
    #pragma unroll
    for (int j = 0; j < 2; j++)
      bg[j] = ld8(&shB[(wn + j * 16 + l16) * 32 + quad * 8]);
    #pragma unroll
    for (int i = 0; i < 4; i++)
      #pragma unroll
      for (int j = 0; j < 2; j++)
        acc[i][j] = __builtin_amdgcn_mfma_f32_16x16x32_bf16(af[i], bg[j], acc[i][j], 0, 0, 0);
    __syncthreads();
  }

  // epilogue; C/D layout: col = lane&15, row = quad*4 + reg
  #pragma unroll
  for (int i = 0; i < 4; i++) {
    #pragma unroll
    for (int j = 0; j < 2; j++) {
      int gn = bn0 + wn + j * 16 + l16;
      float bv = bias[gn];
      int gm0 = bm0 + i * 16 + quad * 4;
      #pragma unroll
      for (int r = 0; r < 4; r++)
        outf[(size_t)(gm0 + r) * D_MODEL + gn] = acc[i][j][r] + bv;
    }
  }
}

// ---------------- flash attention (causal) v22: 128-key tiles, half the barriers ----------------
// v16 residual analysis: per-step cost ~4.45k cyc vs ~2k of co-resident work ->
// barrier/drain overhead paid 34x/CU dominates. v22 stages 128 keys per round
// (v9's verified K/V layout) and computes TWO 64-key halves per barrier with v13's
// frag-sharing body -> 17 barriers/CU instead of 34. PT shrinks to 16 rows with
// sequential g0->g1 reuse (HW-verified correct in v18/v19) to keep LDS at
// 32K(Kdbuf)+32K(Vdbuf)+9.2K(PT) = 74.75KB -> still 2 blocks/CU (v16 pairing kept).
__global__ __launch_bounds__(256)
void attn_k(const bf16* __restrict__ Qp, const bf16* __restrict__ Kp,
            const bf16* __restrict__ Vtp, bf16* __restrict__ Obuf) {
  __shared__ __align__(16) bf16 shK[2][128 * 64];  // 32 KB [buf][key][swizzled d-chunk]
  __shared__ __align__(16) bf16 shV[2][64 * 128];  // 32 KB [buf][d][swizzled key-chunk]
  __shared__ __align__(16) bf16 shPT[4][16 * 72];  // 9.2 KB per-wave P^T (seq groups)
  const int tid  = threadIdx.x;
  const int wave = tid >> 6, lane = tid & 63;
  const int quad = lane >> 4, l16 = lane & 15;
  const int bx = blockIdx.x;
  const int g = bx >> 5;
  const int qb = (g < 8) ? g : 23 - g;   // complementary pairing: NT sums to 17/CU
  const int bh = bx & 31;                // same-head blocks: id stride 32 -> same XCD
  const int qw0 = qb * 128 + wave * 32;  // first of this wave's 32 q rows

  const bf16* Qbh = Qp  + (size_t)bh * SEQ * 64;
  const bf16* Kbh = Kp  + (size_t)bh * SEQ * 64;
  const bf16* Vbh = Vtp + (size_t)bh * 64 * SEQ;

  // Q as B-operand frags, two 16-row groups
  bf16x8 aQ[2][2];
  #pragma unroll
  for (int g2 = 0; g2 < 2; g2++)
    #pragma unroll
    for (int p = 0; p < 2; p++)
      aQ[g2][p] = ld8(&Qbh[(size_t)(qw0 + g2 * 16 + l16) * 64 + p * 32 + quad * 8]);

  f32x4 o0[4], o1[4];
  #pragma unroll
  for (int j = 0; j < 4; j++) { o0[j] = (f32x4){0.f,0.f,0.f,0.f}; o1[j] = (f32x4){0.f,0.f,0.f,0.f}; }
  f32x4 lacc0 = (f32x4){0.f,0.f,0.f,0.f}, lacc1 = (f32x4){0.f,0.f,0.f,0.f};
  const int qlane0 = qw0 + l16, qlane1 = qw0 + 16 + l16;
  const int xq = l16 & 7;             // read-side swizzle key

  const float SC = 0.125f * LOG2E;
  bf16* PT = shPT[wave];

  // ---- prologue: stage 128-key tile 0 into buf 0 (v9-verified swizzled layout) ----
  #pragma unroll
  for (int s2 = 0; s2 < 4; s2++) {
    int id = tid + s2 * 256;           // 0..1023
    int kr = id >> 3, kc = id & 7;
    async16(&Kbh[(size_t)kr * 64 + (kc ^ (kr & 7)) * 8], &shK[0][id * 8]);
  }
  #pragma unroll
  for (int s2 = 0; s2 < 4; s2++) {
    int id = tid + s2 * 256;
    int vd = id >> 4, vc = id & 15;
    int svc = (vc & 8) | ((vc & 7) ^ (vd & 7));
    async16(&Vbh[(size_t)vd * SEQ + svc * 8], &shV[0][id * 8]);
  }
  __syncthreads();   // drains vmcnt -> tile 0 resident

  const int NT = qb + 1;              // 128-key tiles
  int cur = 0;
  for (int kt = 0; kt < NT; kt++) {
    // ---- issue stage of tile kt+1 into buf^1 (hidden under this tile's compute) ----
    if (kt + 1 < NT) {
      const int kb1 = (kt + 1) * 128;
      #pragma unroll
      for (int s2 = 0; s2 < 4; s2++) {
        int id = tid + s2 * 256;
        int kr = id >> 3, kc = id & 7;
        async16(&Kbh[(size_t)(kb1 + kr) * 64 + (kc ^ (kr & 7)) * 8],
                &shK[cur ^ 1][id * 8]);
      }
      #pragma unroll
      for (int s2 = 0; s2 < 4; s2++) {
        int id = tid + s2 * 256;
        int vd = id >> 4, vc = id & 15;
        int svc = (vc & 8) | ((vc & 7) ^ (vd & 7));
        async16(&Vbh[(size_t)vd * SEQ + kb1 + svc * 8], &shV[cur ^ 1][id * 8]);
      }
    }

    const bf16* Kb = shK[cur];
    const bf16* Vb = shV[cur];

    #pragma unroll
    for (int h = 0; h < 2; h++) {
      const int hb = kt * 128 + h * 64;
      if (hb > qw0 + 31) continue;     // wave-uniform (no barrier inside)

      // ---- S^T = K*Q^T, both q-groups off the SAME K-frag reads ----
      f32x4 st0[4], st1[4];
      __builtin_amdgcn_s_setprio(1);
      #pragma unroll
      for (int c = 0; c < 4; c++) {
        int kr0 = h * 64 + c * 16 + l16;             // kr0&7 == xq
        bf16x8 kf0 = ld8(&Kb[kr0 * 64 + ((quad    ) ^ xq) * 8]);
        bf16x8 kf1 = ld8(&Kb[kr0 * 64 + ((quad + 4) ^ xq) * 8]);
        f32x4 a0 = (f32x4){0.f,0.f,0.f,0.f};
        a0 = __builtin_amdgcn_mfma_f32_16x16x32_bf16(kf0, aQ[0][0], a0, 0, 0, 0);
        a0 = __builtin_amdgcn_mfma_f32_16x16x32_bf16(kf1, aQ[0][1], a0, 0, 0, 0);
        f32x4 a1 = (f32x4){0.f,0.f,0.f,0.f};
        a1 = __builtin_amdgcn_mfma_f32_16x16x32_bf16(kf0, aQ[1][0], a1, 0, 0, 0);
        a1 = __builtin_amdgcn_mfma_f32_16x16x32_bf16(kf1, aQ[1][1], a1, 0, 0, 0);
        st0[c] = a0; st1[c] = a1;      // row=key-local(quad*4+r), col=q(l16)
      }
      __builtin_amdgcn_s_setprio(0);

      // ---- causal mask (diagonal-straddling half only; wave-uniform) ----
      if (hb + 63 > qw0) {
        #pragma unroll
        for (int c = 0; c < 4; c++)
          #pragma unroll
          for (int r = 0; r < 4; r++) {
            int key = hb + c * 16 + quad * 4 + r;
            if (key > qlane0) st0[c][r] = NEG_SENT;
            if (key > qlane1) st1[c][r] = NEG_SENT;
          }
      }

      // ---- fixed-cap softmax, both groups ----
      #pragma unroll
      for (int c = 0; c < 4; c++) {
        #pragma unroll
        for (int r = 0; r < 4; r++) {
          st0[c][r] = exp2f(__builtin_fmaf(st0[c][r], SC, -CAP));
          st1[c][r] = exp2f(__builtin_fmaf(st1[c][r], SC, -CAP));
        }
        lacc0 += st0[c]; lacc1 += st1[c];
      }

      // ---- P^T group 0 -> per-wave LDS, read B-frags (seq reuse, v18-verified) ----
      #pragma unroll
      for (int c = 0; c < 4; c++) {
        bf16x4 p0 = {(bf16)st0[c][0], (bf16)st0[c][1], (bf16)st0[c][2], (bf16)st0[c][3]};
        *(bf16x4*)&PT[l16 * 72 + c * 16 + quad * 4] = p0;
      }
      asm volatile("s_waitcnt lgkmcnt(0)" ::: "memory");
      bf16x8 bP00 = ld8(&PT[l16 * 72 + quad * 8]);
      bf16x8 bP01 = ld8(&PT[l16 * 72 + 32 + quad * 8]);

      // ---- P^T group 1 overwrites (per-wave DS in-order) ----
      #pragma unroll
      for (int c = 0; c < 4; c++) {
        bf16x4 p1 = {(bf16)st1[c][0], (bf16)st1[c][1], (bf16)st1[c][2], (bf16)st1[c][3]};
        *(bf16x4*)&PT[l16 * 72 + c * 16 + quad * 4] = p1;
      }
      asm volatile("s_waitcnt lgkmcnt(0)" ::: "memory");
      bf16x8 bP10 = ld8(&PT[l16 * 72 + quad * 8]);
      bf16x8 bP11 = ld8(&PT[l16 * 72 + 32 + quad * 8]);

      // ---- O^T += V^T * P^T (key chunks h*8+quad, h*8+quad+4; low-3 swizzled) ----
      __builtin_amdgcn_s_setprio(1);
      #pragma unroll
      for (int j = 0; j < 4; j++) {
        int d = j * 16 + l16;                        // d&7 == xq
        bf16x8 v0 = ld8(&Vb[d * 128 + ((h * 8) | ((quad    ) ^ xq)) * 8]);
        bf16x8 v1 = ld8(&Vb[d * 128 + ((h * 8) | ((quad + 4) ^ xq)) * 8]);
        o0[j] = __builtin_amdgcn_mfma_f32_16x16x32_bf16(v0, bP00, o0[j], 0, 0, 0);
        o0[j] = __builtin_amdgcn_mfma_f32_16x16x32_bf16(v1, bP01, o0[j], 0, 0, 0);
        o1[j] = __builtin_amdgcn_mfma_f32_16x16x32_bf16(v0, bP10, o1[j], 0, 0, 0);
        o1[j] = __builtin_amdgcn_mfma_f32_16x16x32_bf16(v1, bP11, o1[j], 0, 0, 0);
      }
      __builtin_amdgcn_s_setprio(0);
    }

    __syncthreads();   // drains vmcnt+lgkm -> tile kt+1 resident; buf^1 readers done
    cur ^= 1;
  }

  // ---- final l reduction + store, both groups ----
  const int b = bh >> 4, h = bh & 15;
  {
    float lr0 = (lacc0[0] + lacc0[1]) + (lacc0[2] + lacc0[3]);
    lr0 += __shfl_xor(lr0, 16, 64);
    lr0 += __shfl_xor(lr0, 32, 64);
    float lr1 = (lacc1[0] + lacc1[1]) + (lacc1[2] + lacc1[3]);
    lr1 += __shfl_xor(lr1, 16, 64);
    lr1 += __shfl_xor(lr1, 32, 64);
    float inv0 = 1.0f / lr0, inv1 = 1.0f / lr1;
    size_t base0 = ((size_t)(b * SEQ + qw0 + l16)) * D_MODEL + h * 64;
    size_t base1 = ((size_t)(b * SEQ + qw0 + 16 + l16)) * D_MODEL + h * 64;
    #pragma unroll
    for (int j = 0; j < 4; j++) {
      bf16x4 ov0 = {(bf16)(o0[j][0] * inv0), (bf16)(o0[j][1] * inv0),
                    (bf16)(o0[j][2] * inv0), (bf16)(o0[j][3] * inv0)};
      bf16x4 ov1 = {(bf16)(o1[j][0] * inv1), (bf16)(o1[j][1] * inv1),
                    (bf16)(o1[j][2] * inv1), (bf16)(o1[j][3] * inv1)};
      *(bf16x4*)&Obuf[base0 + j * 16 + quad * 4] = ov0;
      *(bf16x4*)&Obuf[base1 + j * 16 + quad * 4] = ov1;
    }
  }
}

extern "C" void kernel_launch(void* const* d_in, const int* in_sizes, int n_in,
                              void* d_out, int out_size, void* d_ws, size_t ws_size,
                              hipStream_t stream) {
  const float* x    = (const float*)d_in[0];   // (2,2048,1024) fp32
  const float* Wqkv = (const float*)d_in[1];   // (1024,3072)  fp32
  const float* bqkv = (const float*)d_in[2];   // (3072,)      fp32
  const float* Wout = (const float*)d_in[3];   // (1024,1024)  fp32
  const float* bout = (const float*)d_in[4];   // (1024,)      fp32
  float* out = (float*)d_out;                  // (2,2048,1024) fp32

  char* ws = (char*)d_ws;
  bf16* x16    = (bf16*)(ws);                     //  8 MB; reused as Obuf after gemm0
  bf16* Wqkv_t = (bf16*)(ws + 8388608);           //  6 MB
  bf16* Wout_t = (bf16*)(ws + 14680064);          //  2 MB
  bf16* Qp     = (bf16*)(ws + 16777216);          //  8 MB
  bf16* Kp     = (bf16*)(ws + 25165824);          //  8 MB
  bf16* Vtp    = (bf16*)(ws + 33554432);          //  8 MB  -> total 40 MB
  bf16* Obuf   = x16;

  prep<<<8192, 256, 0, stream>>>(x, x16, Wqkv, Wqkv_t, Wout, Wout_t);

  gemm_bt<<<dim3(3072 / 128, 4096 / 128), 256, 0, stream>>>(
      x16, Wqkv_t, bqkv, nullptr, Qp, Kp, Vtp, 3072, 0);

  attn_k<<<dim3(512), 256, 0, stream>>>(Qp, Kp, Vtp, Obuf);

  gemm_out<<<dim3(1024 / 128, 4096 / 64), 256, 0, stream>>>(
      Obuf, Wout_t, bout, out);
}

// Round 16
// 188.116 us; speedup vs baseline: 1.1268x; 1.0074x over previous
//
#include <hip/hip_runtime.h>
#include <hip/hip_bf16.h>
#include <stdint.h>

typedef __bf16 bf16;
typedef __bf16 bf16x4 __attribute__((ext_vector_type(4)));
typedef __bf16 bf16x8 __attribute__((ext_vector_type(8)));
typedef float  f32x4  __attribute__((ext_vector_type(4)));

#define D_MODEL 1024
#define N_HEADS 16
#define HEAD_DIM 64
#define SEQ 2048
#define BATCH 2
#define LOG2E 1.4426950408889634f
#define NEG_SENT -3.0e4f   // finite "-inf": exp2 underflows to 0; never NaNs
#define CAP 24.0f          // fixed softmax cap (log2 domain); |s*SC| << 127-24

__device__ __forceinline__ bf16x8 ld8(const bf16* p) { return *(const bf16x8*)p; }

__device__ __forceinline__ void async16(const bf16* g, bf16* l) {
  __builtin_amdgcn_global_load_lds(
      (const __attribute__((address_space(1))) void*)g,
      (__attribute__((address_space(3))) void*)l, 16, 0, 0);
}

// ---------------- fused prep: x fp32->bf16 convert + both weight transposes ----------------
__global__ __launch_bounds__(256)
void prep(const float* __restrict__ x, bf16* __restrict__ x16,
          const float* __restrict__ Wqkv, bf16* __restrict__ Wqkv_t,
          const float* __restrict__ Wout, bf16* __restrict__ Wout_t) {
  __shared__ float tile[32][33];
  const int blk = blockIdx.x, tid = threadIdx.x;
  if (blk < 4096) {
    int i = (blk * 256 + tid) * 4;
    float4 v = *(const float4*)&x[i];
    bf16 o[4] = {(bf16)v.x, (bf16)v.y, (bf16)v.z, (bf16)v.w};
    *(uint2*)&x16[i] = *(uint2*)o;
    return;
  }
  const float* in; bf16* out; int R, C, c0, r0;
  if (blk < 7168) {
    int b = blk - 4096;
    in = Wqkv; out = Wqkv_t; R = 1024; C = 3072;
    c0 = (b % 96) * 32; r0 = (b / 96) * 32;
  } else {
    int b = blk - 7168;
    in = Wout; out = Wout_t; R = 1024; C = 1024;
    c0 = (b % 32) * 32; r0 = (b / 32) * 32;
  }
  const int tx = tid & 31, ty = tid >> 5;
  #pragma unroll
  for (int i = 0; i < 32; i += 8)
    tile[ty + i][tx] = in[(size_t)(r0 + ty + i) * C + c0 + tx];
  __syncthreads();
  #pragma unroll
  for (int i = 0; i < 32; i += 8)
    out[(size_t)(c0 + ty + i) * R + r0 + tx] = (bf16)tile[tx][ty + i];
}

// ---------------- GEMM v23: BK=64 via TWO independent [128][32] buffers ----------------
// Ledger: v14b(+19.8) = BK64 bad-layout + bounce; v15(+7.3) = BK64 swizzled + bounce;
// v21(+16.7) = BK32 + bounce alone. Subtracting the isolated bounce: conflict-free
// BK=64 = -9.4us. v23 realizes it with ZERO layout change: two [128][32] buffers per
// operand (v13's exact staging map + fragment addressing, run twice per barrier).
// 16 iterations, 32 MFMA/barrier, LDS 32KB (occupancy still VGPR-bound). Epilogue
// = v13 exact (bounce permanently rejected).
__global__ __launch_bounds__(256)
void gemm_bt(const bf16* __restrict__ A, const bf16* __restrict__ Bt,
             const float* __restrict__ bias, float* __restrict__ outf,
             bf16* __restrict__ Qp, bf16* __restrict__ Kp, bf16* __restrict__ Vtp,
             int N, int mode) {
  __shared__ __align__(16) bf16 shA[2][128 * 32];
  __shared__ __align__(16) bf16 shB[2][128 * 32];
  const int tid  = threadIdx.x;
  const int bm0  = blockIdx.y * 128, bn0 = blockIdx.x * 128;
  const int wave = tid >> 6, lane = tid & 63;
  const int quad = lane >> 4, l16 = lane & 15;
  const int wm = (wave >> 1) * 64, wn = (wave & 1) * 64;

  const int c_lo  = tid;
  const int row_lo = c_lo >> 2,  col_lo = (c_lo & 3) << 3;
  const int c_hi  = tid + 256;
  const int row_hi = c_hi >> 2,  col_hi = (c_hi & 3) << 3;
  const int cb_lo = (wave * 64) * 8;
  const int cb_hi = (256 + wave * 64) * 8;

  f32x4 acc[4][4];
  #pragma unroll
  for (int i = 0; i < 4; i++)
    #pragma unroll
    for (int j = 0; j < 4; j++)
      acc[i][j] = (f32x4){0.f, 0.f, 0.f, 0.f};

  for (int k0 = 0; k0 < 1024; k0 += 64) {
    #pragma unroll
    for (int kk = 0; kk < 2; kk++) {
      const int kb = k0 + kk * 32;
      async16(&A[(size_t)(bm0 + row_lo) * 1024 + kb + col_lo], &shA[kk][cb_lo]);
      async16(&A[(size_t)(bm0 + row_hi) * 1024 + kb + col_hi], &shA[kk][cb_hi]);
      async16(&Bt[(size_t)(bn0 + row_lo) * 1024 + kb + col_lo], &shB[kk][cb_lo]);
      async16(&Bt[(size_t)(bn0 + row_hi) * 1024 + kb + col_hi], &shB[kk][cb_hi]);
    }
    __syncthreads();
    #pragma unroll
    for (int kk = 0; kk < 2; kk++) {
      bf16x8 af[4], bg[4];
      #pragma unroll
      for (int i = 0; i < 4; i++)
        af[i] = ld8(&shA[kk][(wm + i * 16 + l16) * 32 + quad * 8]);
      #pragma unroll
      for (int j = 0; j < 4; j++)
        bg[j] = ld8(&shB[kk][(wn + j * 16 + l16) * 32 + quad * 8]);
      #pragma unroll
      for (int i = 0; i < 4; i++)
        #pragma unroll
        for (int j = 0; j < 4; j++)
          acc[i][j] = __builtin_amdgcn_mfma_f32_16x16x32_bf16(af[i], bg[j], acc[i][j], 0, 0, 0);
    }
    __syncthreads();
  }

  // epilogue; C/D layout: col = lane&15, row = quad*4 + reg   [verified m89/m91]
  #pragma unroll
  for (int i = 0; i < 4; i++) {
    #pragma unroll
    for (int j = 0; j < 4; j++) {
      int gn = bn0 + wn + j * 16 + l16;
      float bv = bias[gn];
      int gm0 = bm0 + wm + i * 16 + quad * 4;
      if (mode == 1) {
        #pragma unroll
        for (int r = 0; r < 4; r++)
          outf[(size_t)(gm0 + r) * N + gn] = acc[i][j][r] + bv;
      } else {
        int which = gn >> 10, rem = gn & 1023;   // uniform across lanes per j
        int h = rem >> 6, d = rem & 63;
        int b = gm0 >> 11, t0 = gm0 & 2047;
        int bh = b * N_HEADS + h;
        if (which == 2) {
          bf16x4 vv = {(bf16)(acc[i][j][0] + bv), (bf16)(acc[i][j][1] + bv),
                       (bf16)(acc[i][j][2] + bv), (bf16)(acc[i][j][3] + bv)};
          *(bf16x4*)&Vtp[((size_t)bh * 64 + d) * SEQ + t0] = vv;
        } else {
          bf16* dst = (which == 0) ? Qp : Kp;
          #pragma unroll
          for (int r = 0; r < 4; r++)
            dst[((size_t)bh * SEQ + t0 + r) * 64 + d] = (bf16)(acc[i][j][r] + bv);
        }
      }
    }
  }
}

// ---------------- gemm_out v17: output projection, 64x128 tiles -> 512 blocks ----------------
__global__ __launch_bounds__(256)
void gemm_out(const bf16* __restrict__ A, const bf16* __restrict__ Bt,
              const float* __restrict__ bias, float* __restrict__ outf) {
  __shared__ __align__(16) bf16 shA[64 * 32];     // 4 KB
  __shared__ __align__(16) bf16 shB[128 * 32];    // 8 KB
  const int tid  = threadIdx.x;
  const int bm0  = blockIdx.y * 64, bn0 = blockIdx.x * 128;
  const int wave = tid >> 6, lane = tid & 63;
  const int quad = lane >> 4, l16 = lane & 15;
  const int wn = wave * 32;

  f32x4 acc[4][2];
  #pragma unroll
  for (int i = 0; i < 4; i++)
    #pragma unroll
    for (int j = 0; j < 2; j++)
      acc[i][j] = (f32x4){0.f, 0.f, 0.f, 0.f};

  const int srow = tid >> 2, scol = (tid & 3) << 3;   // 64 rows x 32 cols per issue set
  for (int k0 = 0; k0 < 1024; k0 += 32) {
    async16(&A[(size_t)(bm0 + srow) * 1024 + k0 + scol], &shA[tid * 8]);
    async16(&Bt[(size_t)(bn0 + srow) * 1024 + k0 + scol], &shB[tid * 8]);
    async16(&Bt[(size_t)(bn0 + 64 + srow) * 1024 + k0 + scol], &shB[(256 + tid) * 8]);
    __syncthreads();
    bf16x8 af[4], bg[2];
    #pragma unroll
    for (int i = 0; i < 4; i++)
      af[i] = ld8(&shA[(i * 16 + l16) * 32 + quad * 8]);
    #pragma unroll
    for (int j = 0; j < 2; j++)
      bg[j] = ld8(&shB[(wn + j * 16 + l16) * 32 + quad * 8]);
    #pragma unroll
    for (int i = 0; i < 4; i++)
      #pragma unroll
      for (int j = 0; j < 2; j++)
        acc[i][j] = __builtin_amdgcn_mfma_f32_16x16x32_bf16(af[i], bg[j], acc[i][j], 0, 0, 0);
    __syncthreads();
  }

  // epilogue; C/D layout: col = lane&15, row = quad*4 + reg
  #pragma unroll
  for (int i = 0; i < 4; i++) {
    #pragma unroll
    for (int j = 0; j < 2; j++) {
      int gn = bn0 + wn + j * 16 + l16;
      float bv = bias[gn];
      int gm0 = bm0 + i * 16 + quad * 4;
      #pragma unroll
      for (int r = 0; r < 4; r++)
        outf[(size_t)(gm0 + r) * D_MODEL + gn] = acc[i][j][r] + bv;
    }
  }
}

// ---------------- flash attention (causal) v22 EXACT (58.3us best): 128-key tiles ----------------
// (unchanged -- control; 17 barriers/CU, PT sequential-reuse, 74.75KB LDS)
__global__ __launch_bounds__(256)
void attn_k(const bf16* __restrict__ Qp, const bf16* __restrict__ Kp,
            const bf16* __restrict__ Vtp, bf16* __restrict__ Obuf) {
  __shared__ __align__(16) bf16 shK[2][128 * 64];  // 32 KB [buf][key][swizzled d-chunk]
  __shared__ __align__(16) bf16 shV[2][64 * 128];  // 32 KB [buf][d][swizzled key-chunk]
  __shared__ __align__(16) bf16 shPT[4][16 * 72];  // 9.2 KB per-wave P^T (seq groups)
  const int tid  = threadIdx.x;
  const int wave = tid >> 6, lane = tid & 63;
  const int quad = lane >> 4, l16 = lane & 15;
  const int bx = blockIdx.x;
  const int g = bx >> 5;
  const int qb = (g < 8) ? g : 23 - g;   // complementary pairing: NT sums to 17/CU
  const int bh = bx & 31;                // same-head blocks: id stride 32 -> same XCD
  const int qw0 = qb * 128 + wave * 32;  // first of this wave's 32 q rows

  const bf16* Qbh = Qp  + (size_t)bh * SEQ * 64;
  const bf16* Kbh = Kp  + (size_t)bh * SEQ * 64;
  const bf16* Vbh = Vtp + (size_t)bh * 64 * SEQ;

  // Q as B-operand frags, two 16-row groups
  bf16x8 aQ[2][2];
  #pragma unroll
  for (int g2 = 0; g2 < 2; g2++)
    #pragma unroll
    for (int p = 0; p < 2; p++)
      aQ[g2][p] = ld8(&Qbh[(size_t)(qw0 + g2 * 16 + l16) * 64 + p * 32 + quad * 8]);

  f32x4 o0[4], o1[4];
  #pragma unroll
  for (int j = 0; j < 4; j++) { o0[j] = (f32x4){0.f,0.f,0.f,0.f}; o1[j] = (f32x4){0.f,0.f,0.f,0.f}; }
  f32x4 lacc0 = (f32x4){0.f,0.f,0.f,0.f}, lacc1 = (f32x4){0.f,0.f,0.f,0.f};
  const int qlane0 = qw0 + l16, qlane1 = qw0 + 16 + l16;
  const int xq = l16 & 7;             // read-side swizzle key

  const float SC = 0.125f * LOG2E;
  bf16* PT = shPT[wave];

  // ---- prologue: stage 128-key tile 0 into buf 0 (v9-verified swizzled layout) ----
  #pragma unroll
  for (int s2 = 0; s2 < 4; s2++) {
    int id = tid + s2 * 256;           // 0..1023
    int kr = id >> 3, kc = id & 7;
    async16(&Kbh[(size_t)kr * 64 + (kc ^ (kr & 7)) * 8], &shK[0][id * 8]);
  }
  #pragma unroll
  for (int s2 = 0; s2 < 4; s2++) {
    int id = tid + s2 * 256;
    int vd = id >> 4, vc = id & 15;
    int svc = (vc & 8) | ((vc & 7) ^ (vd & 7));
    async16(&Vbh[(size_t)vd * SEQ + svc * 8], &shV[0][id * 8]);
  }
  __syncthreads();   // drains vmcnt -> tile 0 resident

  const int NT = qb + 1;              // 128-key tiles
  int cur = 0;
  for (int kt = 0; kt < NT; kt++) {
    // ---- issue stage of tile kt+1 into buf^1 (hidden under this tile's compute) ----
    if (kt + 1 < NT) {
      const int kb1 = (kt + 1) * 128;
      #pragma unroll
      for (int s2 = 0; s2 < 4; s2++) {
        int id = tid + s2 * 256;
        int kr = id >> 3, kc = id & 7;
        async16(&Kbh[(size_t)(kb1 + kr) * 64 + (kc ^ (kr & 7)) * 8],
                &shK[cur ^ 1][id * 8]);
      }
      #pragma unroll
      for (int s2 = 0; s2 < 4; s2++) {
        int id = tid + s2 * 256;
        int vd = id >> 4, vc = id & 15;
        int svc = (vc & 8) | ((vc & 7) ^ (vd & 7));
        async16(&Vbh[(size_t)vd * SEQ + kb1 + svc * 8], &shV[cur ^ 1][id * 8]);
      }
    }

    const bf16* Kb = shK[cur];
    const bf16* Vb = shV[cur];

    #pragma unroll
    for (int h = 0; h < 2; h++) {
      const int hb = kt * 128 + h * 64;
      if (hb > qw0 + 31) continue;     // wave-uniform (no barrier inside)

      // ---- S^T = K*Q^T, both q-groups off the SAME K-frag reads ----
      f32x4 st0[4], st1[4];
      __builtin_amdgcn_s_setprio(1);
      #pragma unroll
      for (int c = 0; c < 4; c++) {
        int kr0 = h * 64 + c * 16 + l16;             // kr0&7 == xq
        bf16x8 kf0 = ld8(&Kb[kr0 * 64 + ((quad    ) ^ xq) * 8]);
        bf16x8 kf1 = ld8(&Kb[kr0 * 64 + ((quad + 4) ^ xq) * 8]);
        f32x4 a0 = (f32x4){0.f,0.f,0.f,0.f};
        a0 = __builtin_amdgcn_mfma_f32_16x16x32_bf16(kf0, aQ[0][0], a0, 0, 0, 0);
        a0 = __builtin_amdgcn_mfma_f32_16x16x32_bf16(kf1, aQ[0][1], a0, 0, 0, 0);
        f32x4 a1 = (f32x4){0.f,0.f,0.f,0.f};
        a1 = __builtin_amdgcn_mfma_f32_16x16x32_bf16(kf0, aQ[1][0], a1, 0, 0, 0);
        a1 = __builtin_amdgcn_mfma_f32_16x16x32_bf16(kf1, aQ[1][1], a1, 0, 0, 0);
        st0[c] = a0; st1[c] = a1;      // row=key-local(quad*4+r), col=q(l16)
      }
      __builtin_amdgcn_s_setprio(0);

      // ---- causal mask (diagonal-straddling half only; wave-uniform) ----
      if (hb + 63 > qw0) {
        #pragma unroll
        for (int c = 0; c < 4; c++)
          #pragma unroll
          for (int r = 0; r < 4; r++) {
            int key = hb + c * 16 + quad * 4 + r;
            if (key > qlane0) st0[c][r] = NEG_SENT;
            if (key > qlane1) st1[c][r] = NEG_SENT;
          }
      }

      // ---- fixed-cap softmax, both groups ----
      #pragma unroll
      for (int c = 0; c < 4; c++) {
        #pragma unroll
        for (int r = 0; r < 4; r++) {
          st0[c][r] = exp2f(__builtin_fmaf(st0[c][r], SC, -CAP));
          st1[c][r] = exp2f(__builtin_fmaf(st1[c][r], SC, -CAP));
        }
        lacc0 += st0[c]; lacc1 += st1[c];
      }

      // ---- P^T group 0 -> per-wave LDS, read B-frags (seq reuse, v18-verified) ----
      #pragma unroll
      for (int c = 0; c < 4; c++) {
        bf16x4 p0 = {(bf16)st0[c][0], (bf16)st0[c][1], (bf16)st0[c][2], (bf16)st0[c][3]};
        *(bf16x4*)&PT[l16 * 72 + c * 16 + quad * 4] = p0;
      }
      asm volatile("s_waitcnt lgkmcnt(0)" ::: "memory");
      bf16x8 bP00 = ld8(&PT[l16 * 72 + quad * 8]);
      bf16x8 bP01 = ld8(&PT[l16 * 72 + 32 + quad * 8]);

      // ---- P^T group 1 overwrites (per-wave DS in-order) ----
      #pragma unroll
      for (int c = 0; c < 4; c++) {
        bf16x4 p1 = {(bf16)st1[c][0], (bf16)st1[c][1], (bf16)st1[c][2], (bf16)st1[c][3]};
        *(bf16x4*)&PT[l16 * 72 + c * 16 + quad * 4] = p1;
      }
      asm volatile("s_waitcnt lgkmcnt(0)" ::: "memory");
      bf16x8 bP10 = ld8(&PT[l16 * 72 + quad * 8]);
      bf16x8 bP11 = ld8(&PT[l16 * 72 + 32 + quad * 8]);

      // ---- O^T += V^T * P^T (key chunks h*8+quad, h*8+quad+4; low-3 swizzled) ----
      __builtin_amdgcn_s_setprio(1);
      #pragma unroll
      for (int j = 0; j < 4; j++) {
        int d = j * 16 + l16;                        // d&7 == xq
        bf16x8 v0 = ld8(&Vb[d * 128 + ((h * 8) | ((quad    ) ^ xq)) * 8]);
        bf16x8 v1 = ld8(&Vb[d * 128 + ((h * 8) | ((quad + 4) ^ xq)) * 8]);
        o0[j] = __builtin_amdgcn_mfma_f32_16x16x32_bf16(v0, bP00, o0[j], 0, 0, 0);
        o0[j] = __builtin_amdgcn_mfma_f32_16x16x32_bf16(v1, bP01, o0[j], 0, 0, 0);
        o1[j] = __builtin_amdgcn_mfma_f32_16x16x32_bf16(v0, bP10, o1[j], 0, 0, 0);
        o1[j] = __builtin_amdgcn_mfma_f32_16x16x32_bf16(v1, bP11, o1[j], 0, 0, 0);
      }
      __builtin_amdgcn_s_setprio(0);
    }

    __syncthreads();   // drains vmcnt+lgkm -> tile kt+1 resident; buf^1 readers done
    cur ^= 1;
  }

  // ---- final l reduction + store, both groups ----
  const int b = bh >> 4, h = bh & 15;
  {
    float lr0 = (lacc0[0] + lacc0[1]) + (lacc0[2] + lacc0[3]);
    lr0 += __shfl_xor(lr0, 16, 64);
    lr0 += __shfl_xor(lr0, 32, 64);
    float lr1 = (lacc1[0] + lacc1[1]) + (lacc1[2] + lacc1[3]);
    lr1 += __shfl_xor(lr1, 16, 64);
    lr1 += __shfl_xor(lr1, 32, 64);
    float inv0 = 1.0f / lr0, inv1 = 1.0f / lr1;
    size_t base0 = ((size_t)(b * SEQ + qw0 + l16)) * D_MODEL + h * 64;
    size_t base1 = ((size_t)(b * SEQ + qw0 + 16 + l16)) * D_MODEL + h * 64;
    #pragma unroll
    for (int j = 0; j < 4; j++) {
      bf16x4 ov0 = {(bf16)(o0[j][0] * inv0), (bf16)(o0[j][1] * inv0),
                    (bf16)(o0[j][2] * inv0), (bf16)(o0[j][3] * inv0)};
      bf16x4 ov1 = {(bf16)(o1[j][0] * inv1), (bf16)(o1[j][1] * inv1),
                    (bf16)(o1[j][2] * inv1), (bf16)(o1[j][3] * inv1)};
      *(bf16x4*)&Obuf[base0 + j * 16 + quad * 4] = ov0;
      *(bf16x4*)&Obuf[base1 + j * 16 + quad * 4] = ov1;
    }
  }
}

extern "C" void kernel_launch(void* const* d_in, const int* in_sizes, int n_in,
                              void* d_out, int out_size, void* d_ws, size_t ws_size,
                              hipStream_t stream) {
  const float* x    = (const float*)d_in[0];   // (2,2048,1024) fp32
  const float* Wqkv = (const float*)d_in[1];   // (1024,3072)  fp32
  const float* bqkv = (const float*)d_in[2];   // (3072,)      fp32
  const float* Wout = (const float*)d_in[3];   // (1024,1024)  fp32
  const float* bout = (const float*)d_in[4];   // (1024,)      fp32
  float* out = (float*)d_out;                  // (2,2048,1024) fp32

  char* ws = (char*)d_ws;
  bf16* x16    = (bf16*)(ws);                     //  8 MB; reused as Obuf after gemm0
  bf16* Wqkv_t = (bf16*)(ws + 8388608);           //  6 MB
  bf16* Wout_t = (bf16*)(ws + 14680064);          //  2 MB
  bf16* Qp     = (bf16*)(ws + 16777216);          //  8 MB
  bf16* Kp     = (bf16*)(ws + 25165824);          //  8 MB
  bf16* Vtp    = (bf16*)(ws + 33554432);          //  8 MB  -> total 40 MB
  bf16* Obuf   = x16;

  prep<<<8192, 256, 0, stream>>>(x, x16, Wqkv, Wqkv_t, Wout, Wout_t);

  gemm_bt<<<dim3(3072 / 128, 4096 / 128), 256, 0, stream>>>(
      x16, Wqkv_t, bqkv, nullptr, Qp, Kp, Vtp, 3072, 0);

  attn_k<<<dim3(512), 256, 0, stream>>>(Qp, Kp, Vtp, Obuf);

  gemm_out<<<dim3(1024 / 128, 4096 / 64), 256, 0, stream>>>(
      Obuf, Wout_t, bout, out);
}